// Round 15
// baseline (302.005 us; speedup 1.0000x reference)
//
#include <hip/hip_runtime.h>
#include <hip/hip_bf16.h>
#include <math.h>

#define B_    8
#define R_    64
#define C_    16
#define D_    128
#define NPAIR 2016
#define CD    2048
#define PG    10
#define NPG   202
#define XSTR  136
#define NEG_BIG (-1e30f)
#define SCALE 0.022097086912079608f   // 1/sqrt(2048)

typedef __attribute__((ext_vector_type(8))) short short8;
typedef __attribute__((ext_vector_type(4))) float float4v;

// ---- ws layout (ushort offsets) ----
#define WMH  0u         // P split-hi, layout [d][e]
#define WML  16384u
#define WHH  32768u     // hW^T split [n][k]
#define WHL  49152u
#define WGH  65536u     // gW^T split [f][d]
#define WGL  81920u
#define WSH  98304u     // s1W^T plain bf16 [n][k]
#define VECO 131072u    // fp32[257]: mb[0..128), kq[128..256), s0[256]
#define QBKO 131592u    // fp32[512]
#define MO   132616u    // bf16 M[b][r][2048]
#define XTO  1181192u   // bf16 XT[b][cd][64]
#define GTO  2229768u   // bf16 GT[b][cd][64]
#define HO   3278344u   // bf16 H[b][r][2048]

// fast RNE bf16 (inputs finite by construction — no NaN path)
__device__ __forceinline__ unsigned short f2b(float f){
    union { float f; unsigned int u; } v; v.f = f;
    const unsigned int r = v.u + 0x7FFFu + ((v.u >> 16) & 1u);
    return (unsigned short)(r >> 16);
}
__device__ __forceinline__ float b2f(unsigned short u){
    union { unsigned int i; float f; } v; v.i = ((unsigned int)u) << 16; return v.f;
}
__device__ __forceinline__ float lo2f(unsigned int u){
    union { unsigned int i; float f; } v; v.i = u << 16; return v.f;
}
__device__ __forceinline__ float hif2f(unsigned int u){
    union { unsigned int i; float f; } v; v.i = u & 0xffff0000u; return v.f;
}
__device__ __forceinline__ unsigned int pack2(float a, float b){
    return (unsigned int)f2b(a) | ((unsigned int)f2b(b) << 16);
}
__device__ __forceinline__ void split_bf(float v, float* hi, float* lo){
    union { float f; unsigned int u; } x; x.f = v;
    const unsigned int r = (x.u + 0x7FFFu + ((x.u >> 16) & 1u)) & 0xffff0000u;
    union { unsigned int u; float f; } h; h.u = r;
    *hi = h.f; *lo = v - h.f;
}
__device__ __forceinline__ float sigmoid_safe(float x){
    x = fminf(fmaxf(x, -30.f), 30.f);
    return 1.f / (1.f + __expf(-x));
}
// tanh-GELU via sigmoid identity (empirically error-neutral here, R12/R13 data)
__device__ __forceinline__ float gelu_tanh(float x){
    const float u = x*x;
    const float g2 = x*(1.5957691216057308f + 0.07135481627159f*u);
    return x * sigmoid_safe(g2);
}

// ===== launch A: P split + vectors + hW/gW splits + XT transpose (321 blocks) =====
__global__ __launch_bounds__(256) void k_prepA(
    const float* __restrict__ x,
    const float* __restrict__ hW, const float* __restrict__ gW,
    const float* __restrict__ qW, const float* __restrict__ qb,
    const float* __restrict__ kW, const float* __restrict__ kb,
    unsigned short* __restrict__ ws)
{
    __shared__ __align__(16) unsigned short tile[128*69];   // XT staging
    const int bid = blockIdx.x, t = threadIdx.x;
    if (bid < 64){
        __shared__ float sKW[2][128];
        const int e0 = bid*2;
        sKW[t>>7][t&127] = kW[(e0 + (t>>7))*128 + (t&127)];
        __syncthreads();
        const int e = t>>7, d = t&127;
        const float* qr = qW + d*128;
        const float* kr = sKW[e];
        float acc = 0.f;
        #pragma unroll 8
        for (int g = 0; g < 128; g += 4){
            const float4 qv = *reinterpret_cast<const float4*>(qr + g);
            acc += qv.x*kr[g] + qv.y*kr[g+1] + qv.z*kr[g+2] + qv.w*kr[g+3];
        }
        float hi, lo; split_bf(acc, &hi, &lo);
        ws[WMH + d*128 + (e0+e)] = f2b(hi);
        ws[WML + d*128 + (e0+e)] = f2b(lo);
    } else if (bid == 64){
        float* vec = (float*)(ws + VECO);
        if (t < 128){
            float a1 = 0.f, a2 = 0.f;
            #pragma unroll 8
            for (int g = 0; g < 128; g += 4){
                const float4 q4 = *reinterpret_cast<const float4*>(qW + t*128 + g);
                const float4 k4 = *reinterpret_cast<const float4*>(kW + t*128 + g);
                const float4 kb4 = *reinterpret_cast<const float4*>(kb + g);
                const float4 qb4 = *reinterpret_cast<const float4*>(qb + g);
                a1 += q4.x*kb4.x + q4.y*kb4.y + q4.z*kb4.z + q4.w*kb4.w;
                a2 += k4.x*qb4.x + k4.y*qb4.y + k4.z*qb4.z + k4.w*qb4.w;
            }
            vec[t] = a1;        // mb[d]
            vec[128 + t] = a2;  // kq[e]
        } else if (t == 128){
            float a = 0.f;
            for (int g = 0; g < 128; ++g) a = fmaf(qb[g], kb[g], a);
            vec[256] = a;       // s0
        }
    } else if (bid < 193){
        const int j = bid - 65;               // 0..127
        const int mat = j >> 6;               // 0: hW, 1: gW
        const int gid = (j & 63)*256 + t;
        const int n = gid >> 7, k = gid & 127;
        const float* W = (mat==0) ? hW : gW;
        const unsigned int baseh = (mat==0) ? WHH : WGH;
        const unsigned int basel = (mat==0) ? WHL : WGL;
        float hi, lo; split_bf(W[k*128 + n], &hi, &lo);
        ws[baseh + gid] = f2b(hi);
        ws[basel + gid] = f2b(lo);
    } else {
        // XT[b][cd][r] transpose from x
        const int blk = bid - 193;            // 0..127
        const int b = blk >> 4, cd0 = (blk & 15)*128;
        #pragma unroll
        for (int i = 0; i < 32; ++i){
            const int idx = i*256 + t;
            const int r = idx >> 7, cc = idx & 127;
            tile[cc*69 + r] = f2b(x[((size_t)(b*64 + r))*CD + cd0 + cc]);
        }
        __syncthreads();
        const unsigned int base = XTO + (unsigned int)(b*2048 + cd0)*64;
        #pragma unroll
        for (int j = 0; j < 32; ++j){
            const int idx = j*256 + t;
            const int cc = idx >> 6, r = idx & 63;
            ws[base + cc*64 + r] = tile[cc*69 + r];
        }
    }
}

// ===== launch B: [0,128) H | [128,256) M+qbk | [256,384) GT | [384,388) s1W cvt =====
__global__ __launch_bounds__(512) void k_prepB(const float* __restrict__ x,
        const float* __restrict__ gb, const float* __restrict__ s1W,
        unsigned short* __restrict__ ws)
{
    __shared__ __align__(16) unsigned short smem[8832];
    __shared__ float sQ[4];
    const int bid = blockIdx.x, t = threadIdx.x;
    const int w = t >> 6, lane = t & 63, l15 = lane & 15, quad = lane >> 4;

    if (bid < 256){
        const bool isM = (bid >= 128);
        unsigned short* sH = smem;
        const int br0 = (bid & 127) * 4;
        const float* kqf = (const float*)(ws + VECO) + 128;
        const float* mbf = (const float*)(ws + VECO);
        if (t < 4) sQ[t] = 0.f;
        __syncthreads();
        #pragma unroll
        for (int i = 0; i < 4; ++i){
            const int flat = (t + 512*i)*4;
            const int lr = flat >> 11, cd = flat & 2047;
            const float4 v = *reinterpret_cast<const float4*>(x + (size_t)(br0+lr)*CD + cd);
            const int ad = (lr*16 + (cd>>7))*XSTR + lr*8 + (cd & 127);
            uint2 uh;
            uh.x = pack2(v.x, v.y); uh.y = pack2(v.z, v.w);
            *reinterpret_cast<uint2*>(sH + ad) = uh;
            if (isM){
                const float4 kq4 = *reinterpret_cast<const float4*>(kqf + (cd & 127));
                atomicAdd(&sQ[lr], v.x*kq4.x + v.y*kq4.y + v.z*kq4.z + v.w*kq4.w);
            }
        }
        __syncthreads();
        const unsigned short* Bh = isM ? (ws+WMH) : (ws+WHH);
        const unsigned short* Bl = isM ? (ws+WML) : (ws+WHL);
        const float bv = isM ? mbf[w*16 + l15] : 0.f;
        float4v acc[4];
        #pragma unroll
        for (int mt = 0; mt < 4; ++mt){ float4v d = {bv,bv,bv,bv}; acc[mt] = d; }
        #pragma unroll
        for (int ks = 0; ks < 4; ++ks){
            const int ko = ks*32 + quad*8;
            const int bd = (w*16 + l15)*128 + ko;
            const short8 bh = *reinterpret_cast<const short8*>(Bh + bd);
            const short8 bl = *reinterpret_cast<const short8*>(Bl + bd);
            #pragma unroll
            for (int mt = 0; mt < 4; ++mt){
                const int ad = (mt*16 + l15)*XSTR + mt*8 + ko;
                const short8 ah = *reinterpret_cast<const short8*>(sH + ad);
                float4v d = acc[mt];
                d = __builtin_amdgcn_mfma_f32_16x16x32_bf16(ah, bh, d, 0,0,0);
                d = __builtin_amdgcn_mfma_f32_16x16x32_bf16(ah, bl, d, 0,0,0);
                acc[mt] = d;
            }
        }
        const int f = w*16 + l15;
        const unsigned int dsto = isM ? MO : HO;
        #pragma unroll
        for (int mt = 0; mt < 4; ++mt)
        #pragma unroll
        for (int e = 0; e < 4; ++e){
            const int c = quad*4 + e;
            ws[dsto + (size_t)(br0+mt)*CD + c*128 + f] = f2b(acc[mt][e]);
        }
        if (isM && t < 4){
            const float s0 = ((const float*)(ws + VECO))[256];
            ((float*)(ws + QBKO))[br0 + t] = sQ[t] + 16.f*s0;
        }
    } else if (bid < 384){
        // GT[b][c*128+f][r] = sum_d gW[d,f] * x[b,r,c,d] + gb[f]
        unsigned short* tileB = smem;   // [r][d] stride 138
        const int gidx = bid - 256;
        const int b = gidx >> 4, cd0 = (gidx & 15)*128;
        #pragma unroll
        for (int i = 0; i < 16; ++i){
            const int idx = i*512 + t;
            const int r = idx >> 7, dd = idx & 127;
            tileB[r*138 + dd] = f2b(x[(size_t)(b*64 + r)*CD + cd0 + dd]);
        }
        __syncthreads();
        float4v acc[4];
        #pragma unroll
        for (int nt = 0; nt < 4; ++nt){ float4v z = {0.f,0.f,0.f,0.f}; acc[nt] = z; }
        #pragma unroll
        for (int ks = 0; ks < 4; ++ks){
            const int ko = ks*32 + quad*8;
            const int adg = (w*16 + l15)*128 + ko;
            const short8 ah = *reinterpret_cast<const short8*>(ws + WGH + adg);
            const short8 al = *reinterpret_cast<const short8*>(ws + WGL + adg);
            #pragma unroll
            for (int nt = 0; nt < 4; ++nt){
                const short8 bb = *reinterpret_cast<const short8*>(tileB + (nt*16 + l15)*138 + ko);
                float4v d = acc[nt];
                d = __builtin_amdgcn_mfma_f32_16x16x32_bf16(ah, bb, d, 0,0,0);
                d = __builtin_amdgcn_mfma_f32_16x16x32_bf16(al, bb, d, 0,0,0);
                acc[nt] = d;
            }
        }
        #pragma unroll
        for (int nt = 0; nt < 4; ++nt)
        #pragma unroll
        for (int e = 0; e < 4; ++e){
            const int f = w*16 + quad*4 + e;
            const float val = acc[nt][e] + gb[f];
            ws[GTO + (size_t)(b*2048 + cd0 + f)*64 + nt*16 + l15] = f2b(val);
        }
    } else {
        // s1W^T plain bf16 convert
        const int gid = (bid - 384)*4096 + t;
        #pragma unroll
        for (int i = 0; i < 8; ++i){
            const int g = gid + i*512;
            const int n = g >> 7, k = g & 127;
            ws[WSH + g] = f2b(s1W[k*128 + n]);
        }
    }
}

// ==== main fused kernel: grid (b, 202), 512 threads, PG=10, LDS->3 blocks/CU, relaxed reg bound ====
__global__ __launch_bounds__(512, 4) void k_main(
    const float* __restrict__ x, const float* __restrict__ seq_mask,
    const int* __restrict__ row, const int* __restrict__ col,
    const float* __restrict__ hb, const float* __restrict__ s1b,
    const float* __restrict__ s2W, const float* __restrict__ s2b,
    const unsigned short* __restrict__ ws, float* __restrict__ out)
{
    __shared__ __align__(16) unsigned short sX[160*XSTR + 80];  // 10 pairs x 16 c x 128 d (skewed)
    __shared__ __align__(16) unsigned short sAl[16*72];         // rows >= PG stay zero
    __shared__ float sLog[PG*64];
    __shared__ float sOut[PG];
    __shared__ float sMask[16];
    __shared__ int srp[PG], scp[PG];

    const int t = threadIdx.x;
    const int w = t >> 6, lane = t & 63, l15 = lane & 15, quad = lane >> 4;
    const int b = blockIdx.x, p0 = blockIdx.y * PG;

    const float* xb = x + (size_t)b * R_ * CD;
    const unsigned short* Hb = ws + HO + (size_t)b * R_ * CD;

    if (t < PG){
        const int pidx = min(p0 + t, NPAIR - 1);   // clamp for tail group
        srp[t] = row[pidx]; scp[t] = col[pidx]; sOut[t] = 0.f;
    }
    if (t >= 32 && t < 48) sMask[t-32] = seq_mask[b*C_ + (t-32)];
    for (int i = t; i < 16*72; i += 512) sAl[i] = 0;
    for (int i = t; i < PG*64; i += 512) sLog[i] = 0.f;
    __syncthreads();

    // ---- phase 1: fused stage + h-gate: x = xj + sigmoid(Hi-Hj+hb)*(xi-xj) ----
    #pragma unroll 5
    for (int i = 0; i < PG; ++i){
        const int flat = (t + 512*i)*4;
        const int p = flat >> 11, cd = flat & 2047;
        const int ri = srp[p], ci = scp[p];
        const float4 xi = *reinterpret_cast<const float4*>(xb + (size_t)ri*CD + cd);
        const float4 xj = *reinterpret_cast<const float4*>(xb + (size_t)ci*CD + cd);
        const uint2 Hi2 = *reinterpret_cast<const uint2*>(Hb + (size_t)ri*CD + cd);
        const uint2 Hj2 = *reinterpret_cast<const uint2*>(Hb + (size_t)ci*CD + cd);
        const float4 h4 = *reinterpret_cast<const float4*>(hb + (cd & 127));
        const float z0 = sigmoid_safe(lo2f(Hi2.x)  - lo2f(Hj2.x)  + h4.x);
        const float z1 = sigmoid_safe(hif2f(Hi2.x) - hif2f(Hj2.x) + h4.y);
        const float z2 = sigmoid_safe(lo2f(Hi2.y)  - lo2f(Hj2.y)  + h4.z);
        const float z3 = sigmoid_safe(hif2f(Hi2.y) - hif2f(Hj2.y) + h4.w);
        const float v0 = xj.x + z0*(xi.x - xj.x);
        const float v1 = xj.y + z1*(xi.y - xj.y);
        const float v2 = xj.z + z2*(xi.z - xj.z);
        const float v3 = xj.w + z3*(xi.w - xj.w);
        const int ad = (p*16 + (cd>>7))*XSTR + p*8 + (cd & 127);
        uint2 uv; uv.x = pack2(v0,v1); uv.y = pack2(v2,v3);
        *reinterpret_cast<uint2*>(sX + ad) = uv;
    }
    __syncthreads();

    // ---- phase 2: alpha GEMM logits[p][r] = x . M[b,r] (rows >= PG clamped) ----
    {
        const int rt = w & 3, kh = w >> 2;
        const int r = rt*16 + l15;
        const unsigned short* Mr = ws + MO + ((size_t)b*64 + r)*CD + kh*1024;
        const int pr = (l15 < PG) ? l15 : (PG - 1);
        float4v d = {0.f,0.f,0.f,0.f};
        #pragma unroll 8
        for (int ks = 0; ks < 32; ++ks){
            const int k = kh*1024 + ks*32 + quad*8;
            const short8 ah = *reinterpret_cast<const short8*>(
                sX + (pr*16 + (k>>7))*XSTR + pr*8 + (k & 127));
            const short8 bh = *reinterpret_cast<const short8*>(Mr + ks*32 + quad*8);
            d = __builtin_amdgcn_mfma_f32_16x16x32_bf16(ah, bh, d, 0,0,0);
        }
        #pragma unroll
        for (int e = 0; e < 4; ++e){
            const int pp = quad*4 + e;
            if (pp < PG) atomicAdd(&sLog[pp*64 + r], d[e]);
        }
    }
    __syncthreads();

    // ---- masked softmax (threads 0..PG*16: 16 lanes per pair) ----
    if (t < PG*16){
        const int pp = t >> 4, l = t & 15;
        const int ri = srp[pp], ci = scp[pp];
        const float* qbk = (const float*)(ws + QBKO);
        float v[4]; float m = NEG_BIG;
        #pragma unroll
        for (int k = 0; k < 4; ++k){
            const int r = l + 16*k;
            float lv = (sLog[pp*64 + r] + qbk[b*64 + r]) * SCALE;
            if (r == ri || r == ci) lv = NEG_BIG;
            v[k] = lv; m = fmaxf(m, lv);
        }
        #pragma unroll
        for (int s = 1; s < 16; s <<= 1) m = fmaxf(m, __shfl_xor(m, s));
        float e4[4]; float sum = 0.f;
        #pragma unroll
        for (int k = 0; k < 4; ++k){
            const int r = l + 16*k;
            const bool masked = (r == ri || r == ci);
            const float e = masked ? 0.f : __expf(fmaxf(v[k]-m, -80.f));
            e4[k] = e; sum += e;
        }
        #pragma unroll
        for (int s = 1; s < 16; s <<= 1) sum += __shfl_xor(sum, s);
        const float inv = 1.f / sum;
        #pragma unroll
        for (int k = 0; k < 4; ++k) sAl[pp*72 + l + 16*k] = f2b(e4[k]*inv);
    }
    __syncthreads();

    // ---- phase 3: fused xg + g GEMMs (K=64) + gate (pp >= PG discarded; sAl rows 0) ----
    {
        const unsigned short* XTb = ws + XTO + (size_t)b * CD * 64;
        const unsigned short* GTb = ws + GTO + (size_t)b * CD * 64;
        const short8 Ah0 = *reinterpret_cast<const short8*>(sAl + l15*72 + quad*8);
        const short8 Ah1 = *reinterpret_cast<const short8*>(sAl + l15*72 + 32 + quad*8);
        #pragma unroll 4
        for (int j = 0; j < 16; ++j){
            const int cd = w*256 + j*16 + l15;
            const short8 xb0 = *reinterpret_cast<const short8*>(XTb + (size_t)cd*64 + quad*8);
            const short8 xb1 = *reinterpret_cast<const short8*>(XTb + (size_t)cd*64 + 32 + quad*8);
            const short8 gb0 = *reinterpret_cast<const short8*>(GTb + (size_t)cd*64 + quad*8);
            const short8 gb1 = *reinterpret_cast<const short8*>(GTb + (size_t)cd*64 + 32 + quad*8);
            float4v dx = {0.f,0.f,0.f,0.f}, dg = {0.f,0.f,0.f,0.f};
            dx = __builtin_amdgcn_mfma_f32_16x16x32_bf16(Ah0, xb0, dx, 0,0,0);
            dx = __builtin_amdgcn_mfma_f32_16x16x32_bf16(Ah1, xb1, dx, 0,0,0);
            dg = __builtin_amdgcn_mfma_f32_16x16x32_bf16(Ah0, gb0, dg, 0,0,0);
            dg = __builtin_amdgcn_mfma_f32_16x16x32_bf16(Ah1, gb1, dg, 0,0,0);
            #pragma unroll
            for (int e = 0; e < 4; ++e){
                const int pp = quad*4 + e;
                if (pp < PG){
                    const int ad = (pp*16 + (cd>>7))*XSTR + pp*8 + (cd & 127);
                    const float wv = sigmoid_safe(dg[e]);
                    const float xo = b2f(sX[ad]);
                    sX[ad] = f2b((1.f - wv)*xo + wv*dx[e]);
                }
            }
        }
    }
    __syncthreads();

    // ---- phase 4: s1-GEMM (M=160, single-bf16 weights) + tanh-gelu + reduce ----
    {
        float4v acc10[PG];
        const float bv = s1b[w*16 + l15];
        #pragma unroll
        for (int mt = 0; mt < PG; ++mt){ float4v d = {bv,bv,bv,bv}; acc10[mt] = d; }
        #pragma unroll
        for (int ks = 0; ks < 4; ++ks){
            const int ko = ks*32 + quad*8;
            const int bd = (w*16 + l15)*128 + ko;
            const short8 bh = *reinterpret_cast<const short8*>(ws + WSH + bd);
            #pragma unroll
            for (int mt = 0; mt < PG; ++mt){
                const short8 a = *reinterpret_cast<const short8*>(sX + (mt*16 + l15)*XSTR + mt*8 + ko);
                acc10[mt] = __builtin_amdgcn_mfma_f32_16x16x32_bf16(a, bh, acc10[mt], 0,0,0);
            }
        }
        const float s2v = s2W[w*16 + l15];
        const float mk0 = sMask[quad*4+0], mk1 = sMask[quad*4+1];
        const float mk2 = sMask[quad*4+2], mk3 = sMask[quad*4+3];
        float psum[PG];
        #pragma unroll
        for (int mt = 0; mt < PG; ++mt){
            float s = gelu_tanh(acc10[mt][0]) * mk0;
            s += gelu_tanh(acc10[mt][1]) * mk1;
            s += gelu_tanh(acc10[mt][2]) * mk2;
            s += gelu_tanh(acc10[mt][3]) * mk3;
            psum[mt] = s * s2v;
        }
        #pragma unroll
        for (int s = 1; s < 64; s <<= 1)
            #pragma unroll
            for (int mt = 0; mt < PG; ++mt) psum[mt] += __shfl_xor(psum[mt], s);
        if (lane == 0){
            #pragma unroll
            for (int mt = 0; mt < PG; ++mt) atomicAdd(&sOut[mt], psum[mt]);
        }
    }
    __syncthreads();

    if (t < PG && p0 + t < NPAIR){
        float msum = 0.f;
        #pragma unroll
        for (int c = 0; c < 16; ++c) msum += sMask[c];
        out[(size_t)b*NPAIR + p0 + t] = sOut[t] + s2b[0]*msum;
    }
}

extern "C" void kernel_launch(void* const* d_in, const int* in_sizes, int n_in,
                              void* d_out, int out_size, void* d_ws, size_t ws_size,
                              hipStream_t stream)
{
    const float* x    = (const float*)d_in[0];
    const float* mask = (const float*)d_in[1];
    const int*   row  = (const int*)d_in[2];
    const int*   col  = (const int*)d_in[3];
    const float* hW  = (const float*)d_in[4];  const float* hb  = (const float*)d_in[5];
    const float* gW  = (const float*)d_in[6];  const float* gb  = (const float*)d_in[7];
    const float* qW  = (const float*)d_in[8];  const float* qb  = (const float*)d_in[9];
    const float* kW  = (const float*)d_in[10]; const float* kb  = (const float*)d_in[11];
    const float* s1W = (const float*)d_in[12]; const float* s1b = (const float*)d_in[13];
    const float* s2W = (const float*)d_in[14]; const float* s2b = (const float*)d_in[15];

    unsigned short* ws = (unsigned short*)d_ws;

    k_prepA<<<321, 256, 0, stream>>>(x, hW, gW, qW, qb, kW, kb, ws);
    k_prepB<<<388, 512, 0, stream>>>(x, gb, s1W, ws);
    k_main<<<dim3(B_, NPG), 512, 0, stream>>>(x, mask, row, col,
                                              hb, s1b, s2W, s2b,
                                              ws, (float*)d_out);
}

// Round 16
// 235.703 us; speedup vs baseline: 1.2813x; 1.2813x over previous
//
#include <hip/hip_runtime.h>
#include <hip/hip_bf16.h>
#include <math.h>

#define B_    8
#define R_    64
#define C_    16
#define D_    128
#define NPAIR 2016
#define CD    2048
#define PG    16
#define NPG   126
#define XSTR  136
#define NEG_BIG (-1e30f)
#define SCALE 0.022097086912079608f   // 1/sqrt(2048)

typedef __attribute__((ext_vector_type(8))) short short8;
typedef __attribute__((ext_vector_type(4))) float float4v;

// ---- ws layout (ushort offsets) ----
#define WMH  0u         // P split-hi, layout [d][e]
#define WML  16384u
#define WHH  32768u     // hW^T split [n][k]
#define WHL  49152u
#define WGH  65536u     // gW^T split [f][d]
#define WGL  81920u
#define WSH  98304u     // s1W^T plain bf16 [n][k]
#define VECO 131072u    // fp32[257]: mb[0..128), kq[128..256), s0[256]
#define QBKO 131592u    // fp32[512]
#define MO   132616u    // bf16 M[b][r][2048]
#define XTO  1181192u   // bf16 XT[b][cd][64]
#define GTO  2229768u   // bf16 GT[b][cd][64]
#define HO   3278344u   // bf16 H[b][r][2048]

// fast RNE bf16 (inputs finite by construction — no NaN path)
__device__ __forceinline__ unsigned short f2b(float f){
    union { float f; unsigned int u; } v; v.f = f;
    const unsigned int r = v.u + 0x7FFFu + ((v.u >> 16) & 1u);
    return (unsigned short)(r >> 16);
}
__device__ __forceinline__ float b2f(unsigned short u){
    union { unsigned int i; float f; } v; v.i = ((unsigned int)u) << 16; return v.f;
}
__device__ __forceinline__ float lo2f(unsigned int u){
    union { unsigned int i; float f; } v; v.i = u << 16; return v.f;
}
__device__ __forceinline__ float hif2f(unsigned int u){
    union { unsigned int i; float f; } v; v.i = u & 0xffff0000u; return v.f;
}
__device__ __forceinline__ unsigned int pack2(float a, float b){
    return (unsigned int)f2b(a) | ((unsigned int)f2b(b) << 16);
}
__device__ __forceinline__ void split_bf(float v, float* hi, float* lo){
    union { float f; unsigned int u; } x; x.f = v;
    const unsigned int r = (x.u + 0x7FFFu + ((x.u >> 16) & 1u)) & 0xffff0000u;
    union { unsigned int u; float f; } h; h.u = r;
    *hi = h.f; *lo = v - h.f;
}
__device__ __forceinline__ float sigmoid_safe(float x){
    x = fminf(fmaxf(x, -30.f), 30.f);
    return 1.f / (1.f + __expf(-x));
}
// tanh-GELU via sigmoid identity (empirically error-neutral here, R12/R13 data)
__device__ __forceinline__ float gelu_tanh(float x){
    const float u = x*x;
    const float g2 = x*(1.5957691216057308f + 0.07135481627159f*u);
    return x * sigmoid_safe(g2);
}

// ===== launch A: P split + vectors + hW/gW splits + XT transpose (321 blocks) =====
__global__ __launch_bounds__(256) void k_prepA(
    const float* __restrict__ x,
    const float* __restrict__ hW, const float* __restrict__ gW,
    const float* __restrict__ qW, const float* __restrict__ qb,
    const float* __restrict__ kW, const float* __restrict__ kb,
    unsigned short* __restrict__ ws)
{
    __shared__ __align__(16) unsigned short tile[128*69];   // XT staging
    const int bid = blockIdx.x, t = threadIdx.x;
    if (bid < 64){
        __shared__ float sKW[2][128];
        const int e0 = bid*2;
        sKW[t>>7][t&127] = kW[(e0 + (t>>7))*128 + (t&127)];
        __syncthreads();
        const int e = t>>7, d = t&127;
        const float* qr = qW + d*128;
        const float* kr = sKW[e];
        float acc = 0.f;
        #pragma unroll 8
        for (int g = 0; g < 128; g += 4){
            const float4 qv = *reinterpret_cast<const float4*>(qr + g);
            acc += qv.x*kr[g] + qv.y*kr[g+1] + qv.z*kr[g+2] + qv.w*kr[g+3];
        }
        float hi, lo; split_bf(acc, &hi, &lo);
        ws[WMH + d*128 + (e0+e)] = f2b(hi);
        ws[WML + d*128 + (e0+e)] = f2b(lo);
    } else if (bid == 64){
        float* vec = (float*)(ws + VECO);
        if (t < 128){
            float a1 = 0.f, a2 = 0.f;
            #pragma unroll 8
            for (int g = 0; g < 128; g += 4){
                const float4 q4 = *reinterpret_cast<const float4*>(qW + t*128 + g);
                const float4 k4 = *reinterpret_cast<const float4*>(kW + t*128 + g);
                const float4 kb4 = *reinterpret_cast<const float4*>(kb + g);
                const float4 qb4 = *reinterpret_cast<const float4*>(qb + g);
                a1 += q4.x*kb4.x + q4.y*kb4.y + q4.z*kb4.z + q4.w*kb4.w;
                a2 += k4.x*qb4.x + k4.y*qb4.y + k4.z*qb4.z + k4.w*qb4.w;
            }
            vec[t] = a1;        // mb[d]
            vec[128 + t] = a2;  // kq[e]
        } else if (t == 128){
            float a = 0.f;
            for (int g = 0; g < 128; ++g) a = fmaf(qb[g], kb[g], a);
            vec[256] = a;       // s0
        }
    } else if (bid < 193){
        const int j = bid - 65;               // 0..127
        const int mat = j >> 6;               // 0: hW, 1: gW
        const int gid = (j & 63)*256 + t;
        const int n = gid >> 7, k = gid & 127;
        const float* W = (mat==0) ? hW : gW;
        const unsigned int baseh = (mat==0) ? WHH : WGH;
        const unsigned int basel = (mat==0) ? WHL : WGL;
        float hi, lo; split_bf(W[k*128 + n], &hi, &lo);
        ws[baseh + gid] = f2b(hi);
        ws[basel + gid] = f2b(lo);
    } else {
        // XT[b][cd][r] transpose from x
        const int blk = bid - 193;            // 0..127
        const int b = blk >> 4, cd0 = (blk & 15)*128;
        #pragma unroll
        for (int i = 0; i < 32; ++i){
            const int idx = i*256 + t;
            const int r = idx >> 7, cc = idx & 127;
            tile[cc*69 + r] = f2b(x[((size_t)(b*64 + r))*CD + cd0 + cc]);
        }
        __syncthreads();
        const unsigned int base = XTO + (unsigned int)(b*2048 + cd0)*64;
        #pragma unroll
        for (int j = 0; j < 32; ++j){
            const int idx = j*256 + t;
            const int cc = idx >> 6, r = idx & 63;
            ws[base + cc*64 + r] = tile[cc*69 + r];
        }
    }
}

// ===== launch B: [0,128) H | [128,256) M+qbk | [256,384) GT | [384,388) s1W cvt =====
__global__ __launch_bounds__(512) void k_prepB(const float* __restrict__ x,
        const float* __restrict__ gb, const float* __restrict__ s1W,
        unsigned short* __restrict__ ws)
{
    __shared__ __align__(16) unsigned short smem[8832];
    __shared__ float sQ[4];
    const int bid = blockIdx.x, t = threadIdx.x;
    const int w = t >> 6, lane = t & 63, l15 = lane & 15, quad = lane >> 4;

    if (bid < 256){
        const bool isM = (bid >= 128);
        unsigned short* sH = smem;
        const int br0 = (bid & 127) * 4;
        const float* kqf = (const float*)(ws + VECO) + 128;
        const float* mbf = (const float*)(ws + VECO);
        if (t < 4) sQ[t] = 0.f;
        __syncthreads();
        #pragma unroll
        for (int i = 0; i < 4; ++i){
            const int flat = (t + 512*i)*4;
            const int lr = flat >> 11, cd = flat & 2047;
            const float4 v = *reinterpret_cast<const float4*>(x + (size_t)(br0+lr)*CD + cd);
            const int ad = (lr*16 + (cd>>7))*XSTR + lr*8 + (cd & 127);
            uint2 uh;
            uh.x = pack2(v.x, v.y); uh.y = pack2(v.z, v.w);
            *reinterpret_cast<uint2*>(sH + ad) = uh;
            if (isM){
                const float4 kq4 = *reinterpret_cast<const float4*>(kqf + (cd & 127));
                atomicAdd(&sQ[lr], v.x*kq4.x + v.y*kq4.y + v.z*kq4.z + v.w*kq4.w);
            }
        }
        __syncthreads();
        const unsigned short* Bh = isM ? (ws+WMH) : (ws+WHH);
        const unsigned short* Bl = isM ? (ws+WML) : (ws+WHL);
        const float bv = isM ? mbf[w*16 + l15] : 0.f;
        float4v acc[4];
        #pragma unroll
        for (int mt = 0; mt < 4; ++mt){ float4v d = {bv,bv,bv,bv}; acc[mt] = d; }
        #pragma unroll
        for (int ks = 0; ks < 4; ++ks){
            const int ko = ks*32 + quad*8;
            const int bd = (w*16 + l15)*128 + ko;
            const short8 bh = *reinterpret_cast<const short8*>(Bh + bd);
            const short8 bl = *reinterpret_cast<const short8*>(Bl + bd);
            #pragma unroll
            for (int mt = 0; mt < 4; ++mt){
                const int ad = (mt*16 + l15)*XSTR + mt*8 + ko;
                const short8 ah = *reinterpret_cast<const short8*>(sH + ad);
                float4v d = acc[mt];
                d = __builtin_amdgcn_mfma_f32_16x16x32_bf16(ah, bh, d, 0,0,0);
                d = __builtin_amdgcn_mfma_f32_16x16x32_bf16(ah, bl, d, 0,0,0);
                acc[mt] = d;
            }
        }
        const int f = w*16 + l15;
        const unsigned int dsto = isM ? MO : HO;
        #pragma unroll
        for (int mt = 0; mt < 4; ++mt)
        #pragma unroll
        for (int e = 0; e < 4; ++e){
            const int c = quad*4 + e;
            ws[dsto + (size_t)(br0+mt)*CD + c*128 + f] = f2b(acc[mt][e]);
        }
        if (isM && t < 4){
            const float s0 = ((const float*)(ws + VECO))[256];
            ((float*)(ws + QBKO))[br0 + t] = sQ[t] + 16.f*s0;
        }
    } else if (bid < 384){
        // GT[b][c*128+f][r] = sum_d gW[d,f] * x[b,r,c,d] + gb[f]
        unsigned short* tileB = smem;   // [r][d] stride 138
        const int gidx = bid - 256;
        const int b = gidx >> 4, cd0 = (gidx & 15)*128;
        #pragma unroll
        for (int i = 0; i < 16; ++i){
            const int idx = i*512 + t;
            const int r = idx >> 7, dd = idx & 127;
            tileB[r*138 + dd] = f2b(x[(size_t)(b*64 + r)*CD + cd0 + dd]);
        }
        __syncthreads();
        float4v acc[4];
        #pragma unroll
        for (int nt = 0; nt < 4; ++nt){ float4v z = {0.f,0.f,0.f,0.f}; acc[nt] = z; }
        #pragma unroll
        for (int ks = 0; ks < 4; ++ks){
            const int ko = ks*32 + quad*8;
            const int adg = (w*16 + l15)*128 + ko;
            const short8 ah = *reinterpret_cast<const short8*>(ws + WGH + adg);
            const short8 al = *reinterpret_cast<const short8*>(ws + WGL + adg);
            #pragma unroll
            for (int nt = 0; nt < 4; ++nt){
                const short8 bb = *reinterpret_cast<const short8*>(tileB + (nt*16 + l15)*138 + ko);
                float4v d = acc[nt];
                d = __builtin_amdgcn_mfma_f32_16x16x32_bf16(ah, bb, d, 0,0,0);
                d = __builtin_amdgcn_mfma_f32_16x16x32_bf16(al, bb, d, 0,0,0);
                acc[nt] = d;
            }
        }
        #pragma unroll
        for (int nt = 0; nt < 4; ++nt)
        #pragma unroll
        for (int e = 0; e < 4; ++e){
            const int f = w*16 + quad*4 + e;
            const float val = acc[nt][e] + gb[f];
            ws[GTO + (size_t)(b*2048 + cd0 + f)*64 + nt*16 + l15] = f2b(val);
        }
    } else {
        // s1W^T plain bf16 convert
        const int gid = (bid - 384)*4096 + t;
        #pragma unroll
        for (int i = 0; i < 8; ++i){
            const int g = gid + i*512;
            const int n = g >> 7, k = g & 127;
            ws[WSH + g] = f2b(s1W[k*128 + n]);
        }
    }
}

// =========== main fused kernel: grid (b, 126), 512 threads, PG=16 ===========
__global__ __launch_bounds__(512, 4) void k_main(
    const float* __restrict__ x, const float* __restrict__ seq_mask,
    const int* __restrict__ row, const int* __restrict__ col,
    const float* __restrict__ hb, const float* __restrict__ s1b,
    const float* __restrict__ s2W, const float* __restrict__ s2b,
    const unsigned short* __restrict__ ws, float* __restrict__ out)
{
    __shared__ __align__(16) unsigned short sX[256*XSTR + 128];
    __shared__ __align__(16) unsigned short sAl[16*72];
    __shared__ float sLog[1024];
    __shared__ float sOut[PG];
    __shared__ float sMask[16];
    __shared__ int srp[PG], scp[PG];

    const int t = threadIdx.x;
    const int w = t >> 6, lane = t & 63, l15 = lane & 15, quad = lane >> 4;
    const int b = blockIdx.x, p0 = blockIdx.y * PG;
    const float* xb = x + (size_t)b * R_ * CD;
    const unsigned short* Hb = ws + HO + (size_t)b * R_ * CD;

    if (t < PG){ srp[t] = row[p0+t]; scp[t] = col[p0+t]; sOut[t] = 0.f; }
    if (t >= 32 && t < 48) sMask[t-32] = seq_mask[b*C_ + (t-32)];
    for (int i = t; i < 1152; i += 512) sAl[i] = 0;
    for (int i = t; i < 1024; i += 512) sLog[i] = 0.f;
    __syncthreads();

    // ---- phase 1: fused stage + h-gate: x = xj + sigmoid(Hi-Hj+hb)*(xi-xj) ----
    #pragma unroll 4
    for (int i = 0; i < 16; ++i){
        const int flat = (t + 512*i)*4;
        const int p = flat >> 11, cd = flat & 2047;
        const int ri = srp[p], ci = scp[p];
        const float4 xi = *reinterpret_cast<const float4*>(xb + (size_t)ri*CD + cd);
        const float4 xj = *reinterpret_cast<const float4*>(xb + (size_t)ci*CD + cd);
        const uint2 Hi2 = *reinterpret_cast<const uint2*>(Hb + (size_t)ri*CD + cd);
        const uint2 Hj2 = *reinterpret_cast<const uint2*>(Hb + (size_t)ci*CD + cd);
        const float4 h4 = *reinterpret_cast<const float4*>(hb + (cd & 127));
        const float z0 = sigmoid_safe(lo2f(Hi2.x)  - lo2f(Hj2.x)  + h4.x);
        const float z1 = sigmoid_safe(hif2f(Hi2.x) - hif2f(Hj2.x) + h4.y);
        const float z2 = sigmoid_safe(lo2f(Hi2.y)  - lo2f(Hj2.y)  + h4.z);
        const float z3 = sigmoid_safe(hif2f(Hi2.y) - hif2f(Hj2.y) + h4.w);
        const float v0 = xj.x + z0*(xi.x - xj.x);
        const float v1 = xj.y + z1*(xi.y - xj.y);
        const float v2 = xj.z + z2*(xi.z - xj.z);
        const float v3 = xj.w + z3*(xi.w - xj.w);
        const int ad = (p*16 + (cd>>7))*XSTR + p*8 + (cd & 127);
        uint2 uv; uv.x = pack2(v0,v1); uv.y = pack2(v2,v3);
        *reinterpret_cast<uint2*>(sX + ad) = uv;
    }
    __syncthreads();

    // ---- phase 2: alpha GEMM logits[p][r] = x . M[b,r] ----
    {
        const int rt = w & 3, kh = w >> 2;
        const int r = rt*16 + l15;
        const unsigned short* Mr = ws + MO + ((size_t)b*64 + r)*CD + kh*1024;
        float4v d = {0.f,0.f,0.f,0.f};
        #pragma unroll 8
        for (int ks = 0; ks < 32; ++ks){
            const int k = kh*1024 + ks*32 + quad*8;
            const short8 ah = *reinterpret_cast<const short8*>(
                sX + (l15*16 + (k>>7))*XSTR + l15*8 + (k & 127));
            const short8 bh = *reinterpret_cast<const short8*>(Mr + ks*32 + quad*8);
            d = __builtin_amdgcn_mfma_f32_16x16x32_bf16(ah, bh, d, 0,0,0);
        }
        #pragma unroll
        for (int e = 0; e < 4; ++e){
            const int pp = quad*4 + e;
            atomicAdd(&sLog[pp*64 + r], d[e]);
        }
    }
    __syncthreads();

    // ---- masked softmax (threads 0..255: 16 lanes per pair) ----
    if (t < 256){
        const int pp = t >> 4, l = t & 15;
        const int ri = srp[pp], ci = scp[pp];
        const float* qbk = (const float*)(ws + QBKO);
        float v[4]; float m = NEG_BIG;
        #pragma unroll
        for (int k = 0; k < 4; ++k){
            const int r = l + 16*k;
            float lv = (sLog[pp*64 + r] + qbk[b*64 + r]) * SCALE;
            if (r == ri || r == ci) lv = NEG_BIG;
            v[k] = lv; m = fmaxf(m, lv);
        }
        #pragma unroll
        for (int s = 1; s < 16; s <<= 1) m = fmaxf(m, __shfl_xor(m, s));
        float e4[4]; float sum = 0.f;
        #pragma unroll
        for (int k = 0; k < 4; ++k){
            const int r = l + 16*k;
            const bool masked = (r == ri || r == ci);
            const float e = masked ? 0.f : __expf(fmaxf(v[k]-m, -80.f));
            e4[k] = e; sum += e;
        }
        #pragma unroll
        for (int s = 1; s < 16; s <<= 1) sum += __shfl_xor(sum, s);
        const float inv = 1.f / sum;
        #pragma unroll
        for (int k = 0; k < 4; ++k) sAl[pp*72 + l + 16*k] = f2b(e4[k]*inv);
    }
    __syncthreads();

    // ---- phase 3: fused xg + g GEMMs (K=64) + gate ----
    {
        const unsigned short* XTb = ws + XTO + (size_t)b * CD * 64;
        const unsigned short* GTb = ws + GTO + (size_t)b * CD * 64;
        const short8 Ah0 = *reinterpret_cast<const short8*>(sAl + l15*72 + quad*8);
        const short8 Ah1 = *reinterpret_cast<const short8*>(sAl + l15*72 + 32 + quad*8);
        #pragma unroll 4
        for (int j = 0; j < 16; ++j){
            const int cd = w*256 + j*16 + l15;
            const short8 xb0 = *reinterpret_cast<const short8*>(XTb + (size_t)cd*64 + quad*8);
            const short8 xb1 = *reinterpret_cast<const short8*>(XTb + (size_t)cd*64 + 32 + quad*8);
            const short8 gb0 = *reinterpret_cast<const short8*>(GTb + (size_t)cd*64 + quad*8);
            const short8 gb1 = *reinterpret_cast<const short8*>(GTb + (size_t)cd*64 + 32 + quad*8);
            float4v dx = {0.f,0.f,0.f,0.f}, dg = {0.f,0.f,0.f,0.f};
            dx = __builtin_amdgcn_mfma_f32_16x16x32_bf16(Ah0, xb0, dx, 0,0,0);
            dx = __builtin_amdgcn_mfma_f32_16x16x32_bf16(Ah1, xb1, dx, 0,0,0);
            dg = __builtin_amdgcn_mfma_f32_16x16x32_bf16(Ah0, gb0, dg, 0,0,0);
            dg = __builtin_amdgcn_mfma_f32_16x16x32_bf16(Ah1, gb1, dg, 0,0,0);
            #pragma unroll
            for (int e = 0; e < 4; ++e){
                const int pp = quad*4 + e;
                const int ad = (pp*16 + (cd>>7))*XSTR + pp*8 + (cd & 127);
                const float wv = sigmoid_safe(dg[e]);
                const float xo = b2f(sX[ad]);
                sX[ad] = f2b((1.f - wv)*xo + wv*dx[e]);
            }
        }
    }
    __syncthreads();

    // ---- phase 4: s1-GEMM (M=256, single-bf16 weights) + tanh-gelu + reduce ----
    {
        float4v acc16[16];
        const float bv = s1b[w*16 + l15];
        #pragma unroll
        for (int mt = 0; mt < 16; ++mt){ float4v d = {bv,bv,bv,bv}; acc16[mt] = d; }
        #pragma unroll
        for (int ks = 0; ks < 4; ++ks){
            const int ko = ks*32 + quad*8;
            const int bd = (w*16 + l15)*128 + ko;
            const short8 bh = *reinterpret_cast<const short8*>(ws + WSH + bd);
            #pragma unroll
            for (int mt = 0; mt < 16; ++mt){
                const short8 a = *reinterpret_cast<const short8*>(sX + (mt*16 + l15)*XSTR + mt*8 + ko);
                acc16[mt] = __builtin_amdgcn_mfma_f32_16x16x32_bf16(a, bh, acc16[mt], 0,0,0);
            }
        }
        const float s2v = s2W[w*16 + l15];
        const float mk0 = sMask[quad*4+0], mk1 = sMask[quad*4+1];
        const float mk2 = sMask[quad*4+2], mk3 = sMask[quad*4+3];
        float psum[16];
        #pragma unroll
        for (int mt = 0; mt < 16; ++mt){
            float s = gelu_tanh(acc16[mt][0]) * mk0;
            s += gelu_tanh(acc16[mt][1]) * mk1;
            s += gelu_tanh(acc16[mt][2]) * mk2;
            s += gelu_tanh(acc16[mt][3]) * mk3;
            psum[mt] = s * s2v;
        }
        #pragma unroll
        for (int s = 1; s < 64; s <<= 1)
            #pragma unroll
            for (int mt = 0; mt < 16; ++mt) psum[mt] += __shfl_xor(psum[mt], s);
        if (lane == 0){
            #pragma unroll
            for (int mt = 0; mt < 16; ++mt) atomicAdd(&sOut[mt], psum[mt]);
        }
    }
    __syncthreads();

    if (t < PG){
        float msum = 0.f;
        #pragma unroll
        for (int c = 0; c < 16; ++c) msum += sMask[c];
        out[(size_t)b*NPAIR + p0 + t] = sOut[t] + s2b[0]*msum;
    }
}

extern "C" void kernel_launch(void* const* d_in, const int* in_sizes, int n_in,
                              void* d_out, int out_size, void* d_ws, size_t ws_size,
                              hipStream_t stream)
{
    const float* x    = (const float*)d_in[0];
    const float* mask = (const float*)d_in[1];
    const int*   row  = (const int*)d_in[2];
    const int*   col  = (const int*)d_in[3];
    const float* hW  = (const float*)d_in[4];  const float* hb  = (const float*)d_in[5];
    const float* gW  = (const float*)d_in[6];  const float* gb  = (const float*)d_in[7];
    const float* qW  = (const float*)d_in[8];  const float* qb  = (const float*)d_in[9];
    const float* kW  = (const float*)d_in[10]; const float* kb  = (const float*)d_in[11];
    const float* s1W = (const float*)d_in[12]; const float* s1b = (const float*)d_in[13];
    const float* s2W = (const float*)d_in[14]; const float* s2b = (const float*)d_in[15];

    unsigned short* ws = (unsigned short*)d_ws;

    k_prepA<<<321, 256, 0, stream>>>(x, hW, gW, qW, qb, kW, kb, ws);
    k_prepB<<<388, 512, 0, stream>>>(x, gb, s1W, ws);
    k_main<<<dim3(B_, NPG), 512, 0, stream>>>(x, mask, row, col,
                                              hb, s1b, s2W, s2b,
                                              ws, (float*)d_out);
}